// Round 1
// baseline (363.000 us; speedup 1.0000x reference)
//
#include <hip/hip_runtime.h>

#define BB 8
#define LL 8192
#define DD 1024

typedef float nfloat4 __attribute__((ext_vector_type(4)));

// One block per batch. 1024 threads, 8 mask elements per thread (2x int4).
// Block-wide exclusive scan -> destination slot for every input position,
// inverse permutation perm[b*S + dest] = src for dest < S, float 0/1 mask out.
__global__ __launch_bounds__(1024) void build_perm(
    const int* __restrict__ mask, int* __restrict__ perm,
    float* __restrict__ mask_out, int S) {
  const int b = blockIdx.x;
  const int t = threadIdx.x;          // 0..1023
  const int lane = t & 63;
  const int wave = t >> 6;            // 0..15

  __shared__ int wave_sums[16];
  __shared__ int s_total;

  const int* m = mask + (size_t)b * LL;
  const int base_i = t * 8;

  // Vectorized mask load: 2x int4 (32 B per thread, aligned).
  int4 mv0 = ((const int4*)(m + base_i))[0];
  int4 mv1 = ((const int4*)(m + base_i))[1];
  int vals[8] = {mv0.x ? 1 : 0, mv0.y ? 1 : 0, mv0.z ? 1 : 0, mv0.w ? 1 : 0,
                 mv1.x ? 1 : 0, mv1.y ? 1 : 0, mv1.z ? 1 : 0, mv1.w ? 1 : 0};
  int local = 0;
#pragma unroll
  for (int k = 0; k < 8; ++k) local += vals[k];

  // Wave-level inclusive scan of per-thread sums (wave = 64 lanes).
  int incl = local;
#pragma unroll
  for (int off = 1; off < 64; off <<= 1) {
    int up = __shfl_up(incl, off, 64);
    if (lane >= off) incl += up;
  }
  if (lane == 63) wave_sums[wave] = incl;
  __syncthreads();

  // Scan the 16 wave sums in wave 0.
  if (wave == 0 && lane < 16) {
    int v = wave_sums[lane];
#pragma unroll
    for (int off = 1; off < 16; off <<= 1) {
      int up = __shfl_up(v, off, 64);
      if (lane >= off) v += up;
    }
    wave_sums[lane] = v;
    if (lane == 15) s_total = v;
  }
  __syncthreads();

  const int wave_base = (wave == 0) ? 0 : wave_sums[wave - 1];
  const int num_tokens = s_total;
  int run = wave_base + incl - local;  // exclusive count of trues before base_i

#pragma unroll
  for (int k = 0; k < 8; ++k) {
    const int i = base_i + k;
    int dest;
    if (vals[k]) {
      dest = run;                      // rank among true tokens
      run += 1;
    } else {
      dest = num_tokens + (i - run);   // trues first, then falses in order
    }
    if (dest < S) perm[(size_t)b * S + dest] = i;
  }

  // Validity mask output as float 0/1.
  for (int j = t; j < S; j += 1024) {
    mask_out[(size_t)b * S + j] = (j < num_tokens) ? 1.0f : 0.0f;
  }
}

// Gather, MLP-batched: each wave owns G_RPW consecutive output rows; per row a
// lane moves 4x float4 (64 B in flight per lane vs 16 B before). perm entries
// are prefetched as scalar loads (readfirstlane -> provably uniform -> s_load,
// lgkmcnt pipe, doesn't serialize against the NT vector stream). Blocks go
// from 33k x 4 KB to ~2k x 64 KB; all 16 data loads issue before any store.
// Nontemporal both ways: every byte touched exactly once, poison fills evict
// L2/L3 between iterations anyway.
#define G_WPB 4   // waves per block (256 threads)
#define G_RPW 4   // rows per wave

__global__ __launch_bounds__(256) void gather_rows(
    const float* __restrict__ hidden, const int* __restrict__ perm,
    float* __restrict__ out, int S) {
  const int b = blockIdx.y;            // 0..B-1
  const int t = threadIdx.x;
  const int wave = __builtin_amdgcn_readfirstlane(t >> 6);  // uniform -> SGPR
  const int lane = t & 63;
  const int rbase = (blockIdx.x * G_WPB + wave) * G_RPW;    // wave's first row

  const int* __restrict__ permb = perm + (size_t)b * S;
  const float* __restrict__ hb = hidden + (size_t)b * ((size_t)LL * DD);
  float* __restrict__ ob = out + (size_t)b * ((size_t)S * DD);

  // Prefetch source row ids (scalar loads, issued before any vector traffic).
  int src[G_RPW];
#pragma unroll
  for (int i = 0; i < G_RPW; ++i) {
    int r = rbase + i;
    if (r > S - 1) r = S - 1;          // clamp: tail rows load a valid row,
    src[i] = permb[r];                 // store below is guarded by r < S
  }

  // Issue all 16 loads (4 rows x 4 float4/lane), then drain to stores.
  nfloat4 v[G_RPW][4];
#pragma unroll
  for (int i = 0; i < G_RPW; ++i) {
    const nfloat4* __restrict__ in4 =
        (const nfloat4*)(hb + (size_t)src[i] * DD) + lane;
    v[i][0] = __builtin_nontemporal_load(in4);
    v[i][1] = __builtin_nontemporal_load(in4 + 64);
    v[i][2] = __builtin_nontemporal_load(in4 + 128);
    v[i][3] = __builtin_nontemporal_load(in4 + 192);
  }
#pragma unroll
  for (int i = 0; i < G_RPW; ++i) {
    const int r = rbase + i;
    if (r < S) {                        // wave-uniform branch, no divergence
      nfloat4* __restrict__ o4 = (nfloat4*)(ob + (size_t)r * DD) + lane;
      __builtin_nontemporal_store(v[i][0], o4);
      __builtin_nontemporal_store(v[i][1], o4 + 64);
      __builtin_nontemporal_store(v[i][2], o4 + 128);
      __builtin_nontemporal_store(v[i][3], o4 + 192);
    }
  }
}

extern "C" void kernel_launch(void* const* d_in, const int* in_sizes, int n_in,
                              void* d_out, int out_size, void* d_ws, size_t ws_size,
                              hipStream_t stream) {
  const float* hidden = (const float*)d_in[0];
  const int* mask = (const int*)d_in[1];

  // out_size = B*S*D + B*S  ->  S = out_size / (B*(D+1))
  const int S = out_size / (BB * (DD + 1));

  float* out_hidden = (float*)d_out;
  float* out_mask = out_hidden + (size_t)BB * S * DD;
  int* perm = (int*)d_ws;  // B*S ints

  build_perm<<<BB, 1024, 0, stream>>>(mask, perm, out_mask, S);

  const int rows_per_block = G_WPB * G_RPW;  // 16
  gather_rows<<<dim3((S + rows_per_block - 1) / rows_per_block, BB), 256, 0,
                stream>>>(hidden, perm, out_hidden, S);
}